// Round 2
// baseline (339.152 us; speedup 1.0000x reference)
//
#include <hip/hip_runtime.h>
#include <cstdint>

#define GEPS 1e-6f

typedef __attribute__((ext_vector_type(8))) short bf16x8;
typedef __attribute__((ext_vector_type(4))) float f32x4;

__device__ __forceinline__ unsigned short f2bf(float f) {
  unsigned int u = __float_as_uint(f);
  u += 0x7fffu + ((u >> 16) & 1u);
  return (unsigned short)(u >> 16);
}

// Branch-free erf-based exact GELU: A&S 7.1.26, |erf err| <= 1.5e-7.
// ~16 VALU ops + 1 v_exp_f32 vs ~40+ divergent ops for __ocml_erf_f32.
__device__ __forceinline__ float fast_gelu(float h) {
  float z  = h * 0.70710678118654752f;
  float az = __builtin_fabsf(z);
  float t  = __builtin_amdgcn_rcpf(__builtin_fmaf(0.3275911f, az, 1.0f));
  float poly = t * __builtin_fmaf(t, __builtin_fmaf(t, __builtin_fmaf(t,
               __builtin_fmaf(t, 1.061405429f, -1.453152027f),
               1.421413741f), -0.284496736f), 0.254829592f);
  float e  = __builtin_amdgcn_exp2f(z * z * -1.44269504088896341f);
  float er = __builtin_fmaf(-poly, e, 1.0f);        // erf(|z|)
  er = __builtin_copysignf(er, z);
  float h5 = 0.5f * h;
  return __builtin_fmaf(h5, er, h5);                // 0.5h*(1+erf)
}

// Pack W1 [C=256][H=256] fp32 -> bf16 fragment-major for the B-operand of
// mfma_f32_16x16x32_bf16: frag (h_tile, kk) is 1 KB; within it lane l=q*16+tl
// holds B[k = kk*32 + q*8 + j][h = h_tile*16 + tl], j=0..7 contiguous.
__global__ void pack_w1(const float* __restrict__ W1, unsigned short* __restrict__ wt) {
  int k = blockIdx.x;    // 0..255 (C)
  int h = threadIdx.x;   // 0..255 (H)
  float v = W1[k * 256 + h];
  int h_tile = h >> 4, tl = h & 15, kk = k >> 5, q = (k >> 3) & 3, j = k & 7;
  wt[(((h_tile << 3) + kk) << 9) + (q << 7) + (tl << 3) + j] = f2bf(v);
}

__global__ __launch_bounds__(256, 5) void gater_main(
    const float* __restrict__ x, const unsigned short* __restrict__ wt,
    const float* __restrict__ b1, const float* __restrict__ w2,
    const float* __restrict__ b2,
    float* __restrict__ y, float* __restrict__ scores, float* __restrict__ probs,
    float* __restrict__ bg_ws, float* __restrict__ sums)
{
  // 32 KB exactly -> 5 blocks/CU. Rows XOR-swizzled (col8 ^= row&7) instead of
  // padded; same bank spread as the old +8 pad. Scratch aliases the A tile,
  // which is dead after the MFMA fragment loads (extra barrier guards it).
  __shared__ short A_lds[64 * 256];
  float* const sc_lds = (float*)A_lds;           // [4*64]
  float* const p_lds  = (float*)A_lds + 256;     // [64]
  float* const bg_lds = (float*)A_lds + 320;     // [4*256]

  const int tid = threadIdx.x;
  const int wave = tid >> 6;
  const int tok0 = blockIdx.x * 64;     // flat token index (b*N + n)
  const int b = tok0 >> 12;             // N = 4096
  const int n0 = tok0 & 4095;
  const float* xblk = x + (size_t)tok0 * 256;
  const float* xt = xblk + tid * 4;     // this thread's column window

  // ---- stage x tile fp32 -> bf16 into LDS (swizzled rows) ----
  #pragma unroll
  for (int i = 0; i < 16; ++i) {
    int token = i * 4 + wave;
    const float4 v = *(const float4*)(xt + i * 1024);
    unsigned int lo = (unsigned int)f2bf(v.x) | ((unsigned int)f2bf(v.y) << 16);
    unsigned int hi = (unsigned int)f2bf(v.z) | ((unsigned int)f2bf(v.w) << 16);
    int idx = token * 256 + (((tid & 63) << 2) ^ ((token & 7) << 3));
    *(uint2*)&A_lds[idx] = make_uint2(lo, hi);
  }
  __syncthreads();

  const int lane = tid & 63, tl = lane & 15, q = lane >> 4;

  f32x4 acc[4][4];
  #pragma unroll
  for (int mi = 0; mi < 4; ++mi)
    #pragma unroll
    for (int ni = 0; ni < 4; ++ni)
      acc[mi][ni] = (f32x4){0.f, 0.f, 0.f, 0.f};

  const bf16x8* wtv = (const bf16x8*)wt;
  const int aswz = (tl & 7) << 3;
  #pragma unroll
  for (int kk = 0; kk < 8; ++kk) {
    bf16x8 a[4], bb[4];
    #pragma unroll
    for (int mi = 0; mi < 4; ++mi)
      a[mi] = *(const bf16x8*)&A_lds[(mi * 16 + tl) * 256 + ((kk * 32 + q * 8) ^ aswz)];
    #pragma unroll
    for (int ni = 0; ni < 4; ++ni)
      bb[ni] = wtv[((((wave << 2) + ni) << 3) + kk) * 64 + lane];
    #pragma unroll
    for (int mi = 0; mi < 4; ++mi)
      #pragma unroll
      for (int ni = 0; ni < 4; ++ni)
        acc[mi][ni] = __builtin_amdgcn_mfma_f32_16x16x32_bf16(a[mi], bb[ni], acc[mi][ni], 0, 0, 0);
  }
  __syncthreads();   // all A_lds reads done -> safe to alias scratch into it

  // ---- epilogue: gelu(h + b1) . w2, reduce over this wave's 64 H cols ----
  float w2v[4], b1v[4];
  #pragma unroll
  for (int ni = 0; ni < 4; ++ni) {
    int h = wave * 64 + ni * 16 + tl;
    w2v[ni] = w2[h];
    b1v[ni] = b1[h];
  }
  #pragma unroll
  for (int mi = 0; mi < 4; ++mi) {
    #pragma unroll
    for (int r = 0; r < 4; ++r) {
      float s = 0.f;
      #pragma unroll
      for (int ni = 0; ni < 4; ++ni) {
        float hv = acc[mi][ni][r] + b1v[ni];
        s += fast_gelu(hv) * w2v[ni];
      }
      #pragma unroll
      for (int m = 1; m < 16; m <<= 1) s += __shfl_xor(s, m, 64);
      if (tl == 0) sc_lds[wave * 64 + mi * 16 + q * 4 + r] = s;
    }
  }
  __syncthreads();

  if (tid < 64) {
    float s = sc_lds[tid] + sc_lds[64 + tid] + sc_lds[128 + tid] + sc_lds[192 + tid] + b2[0];
    float e = __builtin_amdgcn_exp2f(s * -1.44269504088896341f);
    float p = __builtin_amdgcn_rcpf(1.0f + e);
    size_t g = (size_t)tok0 + tid;
    scores[g] = s;
    probs[g] = p;
    p_lds[tid] = p;
    float ent = -(p * logf(p + GEPS) + (1.0f - p) * logf(1.0f - p + GEPS));
    float sp = p, se = ent;
    #pragma unroll
    for (int m = 1; m < 64; m <<= 1) {
      sp += __shfl_xor(sp, m, 64);
      se += __shfl_xor(se, m, 64);
    }
    if (tid == 0) {
      atomicAdd(&sums[b * 2 + 0], sp);
      atomicAdd(&sums[b * 2 + 1], se);
    }
  }
  __syncthreads();

  // ---- y = x * p (L2/L3-hot re-read of x) + bg partial accumulation ----
  float* const yt = y + ((size_t)b * 4097 + n0) * 256 + tid * 4;
  float4 bg = make_float4(0.f, 0.f, 0.f, 0.f);
  #pragma unroll
  for (int i = 0; i < 16; ++i) {
    float4 xv = *(const float4*)(xt + i * 1024);
    float p = p_lds[i * 4 + wave];
    f32x4 yv = {xv.x * p, xv.y * p, xv.z * p, xv.w * p};
    __builtin_nontemporal_store(yv, (f32x4*)(yt + i * 1024));   // write-once, skip cache
    float bw = 1.0f - p;
    bg.x += xv.x * bw; bg.y += xv.y * bw; bg.z += xv.z * bw; bg.w += xv.w * bw;
  }
  *(float4*)&bg_lds[tid * 4] = bg;
  __syncthreads();
  {
    int c = tid;
    float v = bg_lds[c] + bg_lds[256 + c] + bg_lds[512 + c] + bg_lds[768 + c];
    atomicAdd(&bg_ws[b * 256 + c], v);
  }
}

__global__ void finalize(const float* __restrict__ bg_ws, const float* __restrict__ sums,
                         const int* __restrict__ kp, float* __restrict__ y,
                         float* __restrict__ aux)
{
  int b = blockIdx.x, c = threadIdx.x;
  float sp = sums[b * 2 + 0];
  float denom = fmaxf(4096.0f - sp, GEPS);
  y[((size_t)b * 4097 + 4096) * 256 + c] = bg_ws[b * 256 + c] / denom;
  if (b == 0 && c == 0) {
    float t = (float)kp[0] / 4096.0f;
    float lr = 0.f, le = 0.f;
    for (int i = 0; i < 32; ++i) {
      float r = sums[i * 2 + 0] / 4096.0f;
      lr += (r - t) * (r - t);
      le += sums[i * 2 + 1];
    }
    aux[0] = lr / 32.0f + 0.01f * (le / (32.0f * 4096.0f));
  }
}

extern "C" void kernel_launch(void* const* d_in, const int* in_sizes, int n_in,
                              void* d_out, int out_size, void* d_ws, size_t ws_size,
                              hipStream_t stream) {
  const float* x  = (const float*)d_in[0];
  const float* W1 = (const float*)d_in[1];
  const float* b1 = (const float*)d_in[2];
  const float* w2 = (const float*)d_in[3];
  const float* b2 = (const float*)d_in[4];
  const int*   kp = (const int*)d_in[5];

  float* y = (float*)d_out;
  const size_t Y_ELEMS = (size_t)32 * 4097 * 256;   // 33,562,624
  float* aux    = y + Y_ELEMS;
  float* scores = aux + 1;
  float* probs  = scores + (size_t)32 * 4096;

  unsigned short* wt = (unsigned short*)d_ws;                 // 128 KB bf16 frag-major W1
  float* bg_ws = (float*)((char*)d_ws + 131072);              // 32x256 fp32
  float* sums  = bg_ws + 32 * 256;                            // 32 x {sum_p, sum_ent}

  hipMemsetAsync(bg_ws, 0, (32 * 256 + 64) * sizeof(float), stream);
  pack_w1<<<256, 256, 0, stream>>>(W1, wt);
  gater_main<<<2048, 256, 0, stream>>>(x, wt, b1, w2, b2, y, scores, probs, bg_ws, sums);
  finalize<<<32, 256, 0, stream>>>(bg_ws, sums, kp, y, aux);
}